// Round 10
// baseline (301.430 us; speedup 1.0000x reference)
//
#include <hip/hip_runtime.h>
#include <hip/hip_fp16.h>

// ---------------------------------------------------------------------------
// GCN 2-layer forward:  out = log_softmax( A_hat * relu(A_hat * (x W1) + b1) W2 + b2 )
// A_hat = D^-1/2 (A + I) D^-1/2, deg on dst. Edge index arrives as int32.
//
// R16 (resubmit; prior round failed on infra): multi-row gathers with
// COALESCED col indexing (fixes R15's per-lane col scatter). Cost model from
// R10-R15: wave-gather ~max(20cy, 6cy*lines).
//   pull_agg1: 8 fp8-rows per instruction (8 lane-groups x dwordx4 = 1KB).
//   pull_agg2: 16 fp8-rows per instruction (16 groups x dwordx4).
//   col[e+g] is one 32/64B coalesced load per iteration (L1/L2-hot).
// Self-loop is a real CSR entry (ldeg init 1, col[start]=node). Prologue is
// ONE uint4 load: rowse[node] = (start, end, bits(dinv), 0). Tails are
// branchless via zero-row padding (row N of each table is zeroed).
// T2' gets its own buffer (A2) so its zero row never aliases T1' data.
// GEMMs/partition/swizzle unchanged from R15.
// ---------------------------------------------------------------------------

#define BSHIFT 9
#define BSIZE  512            // nodes per bucket; NB = ceil(N/512) = 196 < 256
#define CAPSHIFT 14           // 16384 edge slots per bucket (mean fill ~8.7K)
#define P2_T   1024
#define P2_I   16             // edges staged per thread in partition pass

using half8  = __attribute__((ext_vector_type(8))) _Float16;
using f32x4  = __attribute__((ext_vector_type(4))) float;

__device__ __forceinline__ unsigned char f32_to_fp8(float v) {
    int p = __builtin_amdgcn_cvt_pk_fp8_f32(v, v, 0, false);
    return (unsigned char)(p & 0xff);
}

// accumulate 4 fp8 (one dword) into acc[0..3]
__device__ __forceinline__ void fp8x4_acc(unsigned int v, float* acc) {
    auto f0 = __builtin_amdgcn_cvt_pk_f32_fp8((int)v, false);
    auto f1 = __builtin_amdgcn_cvt_pk_f32_fp8((int)v, true);
    acc[0] += f0[0]; acc[1] += f0[1]; acc[2] += f1[0]; acc[3] += f1[1];
}

// --- partition edges into fixed-capacity dst-buckets, packed src|dstLocal ---
__global__ __launch_bounds__(1024) void partition_kernel(const int* __restrict__ src,
                                                         const int* __restrict__ dst,
                                                         unsigned int* __restrict__ bucket_fill,
                                                         unsigned int* __restrict__ ebuf,
                                                         int E, int NB) {
    __shared__ unsigned int hist[256];
    __shared__ unsigned int cur[256];
    int t = threadIdx.x;
    if (t < 256) hist[t] = 0u;
    __syncthreads();
    size_t base = (size_t)blockIdx.x * (P2_T * P2_I);
    int sv[P2_I], dv[P2_I];
#pragma unroll
    for (int i = 0; i < P2_I; ++i) {
        size_t idx = base + (size_t)i * P2_T + t;
        if (idx < (size_t)E) {
            sv[i] = src[idx];
            dv[i] = dst[idx];
            atomicAdd(&hist[dv[i] >> BSHIFT], 1u);
        } else dv[i] = -1;
    }
    __syncthreads();
    if (t < NB && hist[t] > 0u)
        cur[t] = ((unsigned int)t << CAPSHIFT) + atomicAdd(&bucket_fill[t], hist[t]);
    __syncthreads();
#pragma unroll
    for (int i = 0; i < P2_I; ++i) {
        if (dv[i] >= 0) {
            int b = dv[i] >> BSHIFT;
            unsigned int pos = atomicAdd(&cur[b], 1u);
            ebuf[pos] = (unsigned int)sv[i] | ((unsigned int)(dv[i] & (BSIZE - 1)) << 17);
        }
    }
}

// --- per-bucket CSR: self-edge injected; rowse=(start,end,dinv) per node ---
__global__ __launch_bounds__(256) void bucket_scatter2_kernel(const unsigned int* __restrict__ ebuf,
                                                              const unsigned int* __restrict__ bfill,
                                                              uint4* __restrict__ rowse,
                                                              float* __restrict__ dinv,
                                                              int* __restrict__ col, int N) {
    __shared__ unsigned int ldeg[BSIZE];
    __shared__ unsigned int lcur[BSIZE];
    __shared__ unsigned int part[256];
    int b = blockIdx.x, t = threadIdx.x;
    int node0 = b << BSHIFT;
    int nn = min(BSIZE, N - node0);
    ldeg[t]       = (t < nn) ? 1u : 0u;          // self edge pre-counted
    ldeg[t + 256] = (t + 256 < nn) ? 1u : 0u;
    __syncthreads();
    unsigned int e0 = (unsigned int)b << CAPSHIFT;
    unsigned int e1 = e0 + bfill[b];
    for (unsigned int e = e0 + t; e < e1; e += 256)
        atomicAdd(&ldeg[ebuf[e] >> 17], 1u);
    __syncthreads();
    unsigned int a0 = ldeg[2 * t], a1 = ldeg[2 * t + 1];
    part[t] = a0 + a1;
    __syncthreads();
    for (int off = 1; off < 256; off <<= 1) {
        unsigned int u = part[t];
        if (t >= off) u += part[t - off];
        __syncthreads();
        part[t] = u;
        __syncthreads();
    }
    unsigned int ex = part[t] - (a0 + a1);
    lcur[2 * t]     = e0 + ex;
    lcur[2 * t + 1] = e0 + ex + a0;
    __syncthreads();
    for (int i = t; i < nn; i += 256) {          // write self edge first
        unsigned int p = lcur[i];
        col[p] = node0 + i;
        lcur[i] = p + 1u;
    }
    __syncthreads();
    for (unsigned int e = e0 + t; e < e1; e += 256) {
        unsigned int p = ebuf[e];
        unsigned int pos = atomicAdd(&lcur[p >> 17], 1u);
        col[pos] = (int)(p & 0x1FFFFu);
    }
    __syncthreads();
    for (int i = t; i < nn; i += 256) {
        unsigned int cnt = ldeg[i];              // deg + 1 (self)
        unsigned int ev = lcur[i];               // row end
        float dv = rsqrtf((float)cnt);
        rowse[node0 + i] = make_uint4(ev - cnt, ev, __float_as_uint(dv), 0u);
        dinv[node0 + i] = dv;
    }
}

// --- swizzle W1 (128x128) and W2 (128x64) into MFMA B-fragment order -------
__global__ __launch_bounds__(256) void swizzle_w_kernel(const float* __restrict__ W1,
                                                        const float* __restrict__ W2,
                                                        __half* __restrict__ w1s,
                                                        __half* __restrict__ w2s) {
    int t = blockIdx.x * 256 + threadIdx.x;
    int stride = gridDim.x * 256;
    for (int i = t; i < 8 * 4 * 64 * 8; i += stride) {   // W1: 8 col-tiles
        int j = i & 7, l = (i >> 3) & 63, s = (i >> 9) & 3, c = i >> 11;
        int k = ((l >> 4) * 8) + j + 32 * s;
        int nn = 16 * c + (l & 15);
        w1s[i] = __float2half(W1[k * 128 + nn]);
    }
    for (int i = t; i < 4 * 4 * 64 * 8; i += stride) {   // W2: 4 col-tiles
        int j = i & 7, l = (i >> 3) & 63, s = (i >> 9) & 3, c = i >> 11;
        int k = ((l >> 4) * 8) + j + 32 * s;
        int nn = 16 * c + (l & 15);
        w2s[i] = __float2half(W2[k * 64 + nn]);
    }
}

// --- GEMM1 (MFMA): Y8[r,128] = fp8( dinv[r] * (X[r,128] @ W1) ), X fp32 ----
__global__ __launch_bounds__(256) void gemm1_mfma_kernel(const float* __restrict__ X,
                                                         const __half* __restrict__ w1s,
                                                         const float* __restrict__ dinv,
                                                         unsigned char* __restrict__ Y8, int n) {
    int t = threadIdx.x;
    int wave = t >> 6, lane = t & 63;
    int quad = lane >> 4, m = lane & 15;
    int rowbase = blockIdx.x * 64 + wave * 16;
    int arow = rowbase + m;
    bool aok = arow < n;
    const float* xr = X + (size_t)arow * 128 + quad * 8;

    half8 afrag[4];
#pragma unroll
    for (int s = 0; s < 4; ++s) {
        float4 p0 = make_float4(0.f, 0.f, 0.f, 0.f), p1 = p0;
        if (aok) {
            p0 = *(const float4*)(xr + s * 32);
            p1 = *(const float4*)(xr + s * 32 + 4);
        }
        afrag[s][0] = (_Float16)p0.x; afrag[s][1] = (_Float16)p0.y;
        afrag[s][2] = (_Float16)p0.z; afrag[s][3] = (_Float16)p0.w;
        afrag[s][4] = (_Float16)p1.x; afrag[s][5] = (_Float16)p1.y;
        afrag[s][6] = (_Float16)p1.z; afrag[s][7] = (_Float16)p1.w;
    }

    const half8* bp = (const half8*)w1s;
    f32x4 acc[8];
#pragma unroll
    for (int c = 0; c < 8; ++c) acc[c] = (f32x4){0.f, 0.f, 0.f, 0.f};
#pragma unroll
    for (int c = 0; c < 8; ++c)
#pragma unroll
        for (int s = 0; s < 4; ++s)
            acc[c] = __builtin_amdgcn_mfma_f32_16x16x32_f16(afrag[s], bp[(c * 4 + s) * 64 + lane], acc[c], 0, 0, 0);

#pragma unroll
    for (int i = 0; i < 4; ++i) {
        int row = rowbase + quad * 4 + i;
        if (row < n) {
            float w = dinv[row];
            unsigned char* yr = Y8 + (size_t)row * 128 + m;
#pragma unroll
            for (int c = 0; c < 8; ++c) yr[c * 16] = f32_to_fp8(acc[c][i] * w);
        }
    }
}

// --- GEMM2 (MFMA): Y8[r,64] = fp8( dinv[r] * (Xh[r,128] @ W2) ), X fp16 ----
__global__ __launch_bounds__(256) void gemm2_mfma_kernel(const __half* __restrict__ X,
                                                         const __half* __restrict__ w2s,
                                                         const float* __restrict__ dinv,
                                                         unsigned char* __restrict__ Y8, int n) {
    int t = threadIdx.x;
    int wave = t >> 6, lane = t & 63;
    int quad = lane >> 4, m = lane & 15;
    int rowbase = blockIdx.x * 64 + wave * 16;
    int arow = rowbase + m;
    bool aok = arow < n;
    const __half* xr = X + (size_t)arow * 128 + quad * 8;

    half8 afrag[4];
#pragma unroll
    for (int s = 0; s < 4; ++s) {
        if (aok) afrag[s] = *(const half8*)(xr + s * 32);
        else     afrag[s] = (half8){0, 0, 0, 0, 0, 0, 0, 0};
    }

    const half8* bp = (const half8*)w2s;
    f32x4 acc[4];
#pragma unroll
    for (int c = 0; c < 4; ++c) acc[c] = (f32x4){0.f, 0.f, 0.f, 0.f};
#pragma unroll
    for (int c = 0; c < 4; ++c)
#pragma unroll
        for (int s = 0; s < 4; ++s)
            acc[c] = __builtin_amdgcn_mfma_f32_16x16x32_f16(afrag[s], bp[(c * 4 + s) * 64 + lane], acc[c], 0, 0, 0);

#pragma unroll
    for (int i = 0; i < 4; ++i) {
        int row = rowbase + quad * 4 + i;
        if (row < n) {
            float w = dinv[row];
            unsigned char* yr = Y8 + (size_t)row * 64 + m;
#pragma unroll
            for (int c = 0; c < 4; ++c) yr[c * 16] = f32_to_fp8(acc[c][i] * w);
        }
    }
}

// --- pull layer 1: H[d] = relu(dinv[d]*(sum T'[col]) + b1), F=128 ----------
// R16: 1 node/wave. lane=(g=lane>>3 edge-slot, u=lane&7 feature-16). One
// dwordx4 gather = 8 rows (1KB). col[e+g] coalesced (1 line). Zero-row pad.
__global__ __launch_bounds__(256) void pull_agg1_kernel(const unsigned char* __restrict__ T8,
                                                        const int* __restrict__ col,
                                                        const uint4* __restrict__ rowse,
                                                        const float* __restrict__ b1,
                                                        __half* __restrict__ H, int N) {
    int node = blockIdx.x * 4 + (threadIdx.x >> 6);
    if (node >= N) return;
    int lane = threadIdx.x & 63;
    int g = lane >> 3, u = lane & 7;
    unsigned int boff = (unsigned int)u << 4;      // 16B per lane, 128B per row

    uint4 rs = rowse[node];
    unsigned int e   = __builtin_amdgcn_readfirstlane(rs.x);
    unsigned int end = __builtin_amdgcn_readfirstlane(rs.y);
    float dv = __uint_as_float(__builtin_amdgcn_readfirstlane(rs.z));
    unsigned int ZR = (unsigned int)N;             // zero row

    float acc[16];
#pragma unroll
    for (int j = 0; j < 16; ++j) acc[j] = 0.f;

    while (e < end) {                              // 16 edges/iter (2 gathers)
        unsigned int ea = e + (unsigned int)g;
        unsigned int eb = ea + 8u;
        unsigned int ca = (unsigned int)col[ea < end ? ea : end - 1u];
        unsigned int cb = (unsigned int)col[eb < end ? eb : end - 1u];
        unsigned int ia = (ea < end) ? ca : ZR;
        unsigned int ib = (eb < end) ? cb : ZR;
        uint4 va = *(const uint4*)(T8 + ia * 128u + boff);
        uint4 vb = *(const uint4*)(T8 + ib * 128u + boff);
        fp8x4_acc(va.x, acc + 0); fp8x4_acc(va.y, acc + 4);
        fp8x4_acc(va.z, acc + 8); fp8x4_acc(va.w, acc + 12);
        fp8x4_acc(vb.x, acc + 0); fp8x4_acc(vb.y, acc + 4);
        fp8x4_acc(vb.z, acc + 8); fp8x4_acc(vb.w, acc + 12);
        e += 16u;
    }

#pragma unroll
    for (int j = 0; j < 16; ++j) {                 // reduce over g (bits 3,4,5)
        acc[j] += __shfl_xor(acc[j], 8);
        acc[j] += __shfl_xor(acc[j], 16);
        acc[j] += __shfl_xor(acc[j], 32);
    }

    if (g == 0) {                                  // 8 lanes write 32B each
        const float4* bp = (const float4*)b1;      // features u*16..u*16+15
        __half2 o[8];
#pragma unroll
        for (int k = 0; k < 4; ++k) {
            float4 bb = bp[u * 4 + k];
            o[2 * k]     = __floats2half2_rn(fmaxf(fmaf(dv, acc[4 * k],     bb.x), 0.f),
                                             fmaxf(fmaf(dv, acc[4 * k + 1], bb.y), 0.f));
            o[2 * k + 1] = __floats2half2_rn(fmaxf(fmaf(dv, acc[4 * k + 2], bb.z), 0.f),
                                             fmaxf(fmaf(dv, acc[4 * k + 3], bb.w), 0.f));
        }
        uint4 s0, s1;
        s0.x = *(unsigned int*)&o[0]; s0.y = *(unsigned int*)&o[1];
        s0.z = *(unsigned int*)&o[2]; s0.w = *(unsigned int*)&o[3];
        s1.x = *(unsigned int*)&o[4]; s1.y = *(unsigned int*)&o[5];
        s1.z = *(unsigned int*)&o[6]; s1.w = *(unsigned int*)&o[7];
        char* hb = (char*)H + (size_t)node * 256 + u * 32;
        *(uint4*)hb = s0;
        *(uint4*)(hb + 16) = s1;
    }
}

// --- pull layer 2 + logsoftmax: out[d] = lsm(dinv[d]*sum + b2), F=64 -------
// R16: 1 node/wave. lane=(g=lane>>2 edge-slot, u=lane&3). One dwordx4 gather
// = 16 rows (64B each, 1 line/row). col[e+g] coalesced. Zero-row pad.
__global__ __launch_bounds__(256) void pull_agg2_kernel(const unsigned char* __restrict__ T8,
                                                        const int* __restrict__ col,
                                                        const uint4* __restrict__ rowse,
                                                        const float* __restrict__ b2,
                                                        float* __restrict__ OUT, int N) {
    int node = blockIdx.x * 4 + (threadIdx.x >> 6);
    if (node >= N) return;
    int lane = threadIdx.x & 63;
    int g = lane >> 2, u = lane & 3;
    unsigned int boff = (unsigned int)u << 4;      // 16B per lane, 64B per row

    uint4 rs = rowse[node];
    unsigned int e   = __builtin_amdgcn_readfirstlane(rs.x);
    unsigned int end = __builtin_amdgcn_readfirstlane(rs.y);
    float dv = __uint_as_float(__builtin_amdgcn_readfirstlane(rs.z));
    unsigned int ZR = (unsigned int)N;

    float acc[16];
#pragma unroll
    for (int j = 0; j < 16; ++j) acc[j] = 0.f;

    while (e < end) {                              // 32 edges/iter (2 gathers)
        unsigned int ea = e + (unsigned int)g;
        unsigned int eb = ea + 16u;
        unsigned int ca = (unsigned int)col[ea < end ? ea : end - 1u];
        unsigned int cb = (unsigned int)col[eb < end ? eb : end - 1u];
        unsigned int ia = (ea < end) ? ca : ZR;
        unsigned int ib = (eb < end) ? cb : ZR;
        uint4 va = *(const uint4*)(T8 + ia * 64u + boff);
        uint4 vb = *(const uint4*)(T8 + ib * 64u + boff);
        fp8x4_acc(va.x, acc + 0); fp8x4_acc(va.y, acc + 4);
        fp8x4_acc(va.z, acc + 8); fp8x4_acc(va.w, acc + 12);
        fp8x4_acc(vb.x, acc + 0); fp8x4_acc(vb.y, acc + 4);
        fp8x4_acc(vb.z, acc + 8); fp8x4_acc(vb.w, acc + 12);
        e += 32u;
    }

#pragma unroll
    for (int j = 0; j < 16; ++j) {                 // reduce over g (bits 2..5)
        acc[j] += __shfl_xor(acc[j], 4);
        acc[j] += __shfl_xor(acc[j], 8);
        acc[j] += __shfl_xor(acc[j], 16);
        acc[j] += __shfl_xor(acc[j], 32);
    }

    // all lanes hold totals for features u*16..u*16+15
    const float4* bp = (const float4*)b2;
    float v[16];
#pragma unroll
    for (int k = 0; k < 4; ++k) {
        float4 bb = bp[u * 4 + k];
        v[4 * k]     = fmaf(dv, acc[4 * k],     bb.x);
        v[4 * k + 1] = fmaf(dv, acc[4 * k + 1], bb.y);
        v[4 * k + 2] = fmaf(dv, acc[4 * k + 2], bb.z);
        v[4 * k + 3] = fmaf(dv, acc[4 * k + 3], bb.w);
    }
    float m = v[0];
#pragma unroll
    for (int j = 1; j < 16; ++j) m = fmaxf(m, v[j]);
    m = fmaxf(m, __shfl_xor(m, 1));
    m = fmaxf(m, __shfl_xor(m, 2));
    float sum = 0.f;
#pragma unroll
    for (int j = 0; j < 16; ++j) sum += __expf(v[j] - m);
    sum += __shfl_xor(sum, 1);
    sum += __shfl_xor(sum, 2);
    float ls = m + logf(sum);

    if (g == 0) {                                  // 4 lanes write 64B each
        float* ob = OUT + (size_t)node * 64 + u * 16;
#pragma unroll
        for (int k = 0; k < 4; ++k) {
            float4 o = make_float4(v[4 * k] - ls, v[4 * k + 1] - ls,
                                   v[4 * k + 2] - ls, v[4 * k + 3] - ls);
            *(float4*)(ob + 4 * k) = o;
        }
    }
}

extern "C" void kernel_launch(void* const* d_in, const int* in_sizes, int n_in,
                              void* d_out, int out_size, void* d_ws, size_t ws_size,
                              hipStream_t stream) {
    const float* x   = (const float*)d_in[0];
    const int*   ei  = (const int*)d_in[1];   // int32 per harness contract
    const float* W1  = (const float*)d_in[2];
    const float* b1  = (const float*)d_in[3];
    const float* W2  = (const float*)d_in[4];
    const float* b2  = (const float*)d_in[5];
    float*       out = (float*)d_out;

    const int N = in_sizes[0] / 128;      // 100000
    const int E = in_sizes[1] / 2;        // 1600000
    const int* src = ei;
    const int* dst = ei + E;
    const int NB = (N + BSIZE - 1) >> BSHIFT;   // dst buckets (196 <= 256)
    const size_t CAPTOT = (size_t)NB << CAPSHIFT;

    // workspace layout
    char* ws = (char*)d_ws;
    size_t off = 0;
    auto alloc = [&](size_t bytes) { void* p = ws + off; off = (off + bytes + 255) & ~(size_t)255; return p; };
    float*        dinv   = (float*)alloc((size_t)N * 4);
    uint4*        rowse  = (uint4*)alloc((size_t)N * 16);       // start,end,dinv
    unsigned int* bf     = (unsigned int*)alloc(256 * 4);       // bucket_fill
    __half*       w1s    = (__half*)alloc(128 * 128 * 2);       // swizzled W1
    __half*       w2s    = (__half*)alloc(128 * 64 * 2);        // swizzled W2
    int*          col    = (int*)alloc(CAPTOT * 4);             // CAP-strided
    unsigned char* A1    = (unsigned char*)alloc((size_t)(N + 1) * 128); // T1' fp8 (+zero row)
    unsigned char* A2    = (unsigned char*)alloc((size_t)(N + 1) * 64);  // T2' fp8 (+zero row)
    __half*       B      = (__half*)alloc((size_t)N * 128 * 2);          // h fp16
    unsigned int* ebuf   = (unsigned int*)alloc(CAPTOT * 4);

    // 0. zero bucket fills + the two zero-pad rows
    hipMemsetAsync(bf, 0, 256 * 4, stream);
    hipMemsetAsync(A1 + (size_t)N * 128, 0, 128, stream);
    hipMemsetAsync(A2 + (size_t)N * 64, 0, 64, stream);

    // 1. CSR build: partition into fixed-capacity buckets -> per-bucket scatter
    partition_kernel<<<(E + P2_T * P2_I - 1) / (P2_T * P2_I), P2_T, 0, stream>>>(src, dst, bf, ebuf, E, NB);
    bucket_scatter2_kernel<<<NB, 256, 0, stream>>>(ebuf, bf, rowse, dinv, col, N);

    // 1b. swizzle weights into MFMA fragment order
    swizzle_w_kernel<<<64, 256, 0, stream>>>(W1, W2, w1s, w2s);

    // 2. T1' = fp8(dinv * (x @ W1)) [MFMA];  h = relu(dinv*(pull) + b1)
    gemm1_mfma_kernel<<<(N + 63) / 64, 256, 0, stream>>>(x, w1s, dinv, A1, N);
    pull_agg1_kernel<<<(N + 3) / 4, 256, 0, stream>>>(A1, col, rowse, b1, B, N);

    // 3. T2' = fp8(dinv * (h @ W2)) [MFMA];  out = logsoftmax(dinv*(pull) + b2)
    gemm2_mfma_kernel<<<(N + 63) / 64, 256, 0, stream>>>(B, w2s, dinv, A2, N);
    pull_agg2_kernel<<<(N + 3) / 4, 256, 0, stream>>>(A2, col, rowse, b2, out, N);
}

// Round 11
// 296.656 us; speedup vs baseline: 1.0161x; 1.0161x over previous
//
#include <hip/hip_runtime.h>
#include <hip/hip_fp16.h>

// ---------------------------------------------------------------------------
// GCN 2-layer forward:  out = log_softmax( A_hat * relu(A_hat * (x W1) + b1) W2 + b2 )
// A_hat = D^-1/2 (A + I) D^-1/2, deg on dst. Edge index arrives as int32.
//
// R17: narrowest line-limited gather configs (R16 lesson: wider rows/instr
// past the line limit only inflates the shfl epilogue; agg2@16rows was
// VALU-bound at 57%).
//   pull_agg1: 2 rows/instr (g=lane>>5, dword/lane of 128B row), acc[4],
//              epilogue 4x shfl_xor(32).
//   pull_agg2: 4 rows/instr (g=lane>>4, dword/lane of 64B row), acc[4],
//              epilogue 8 shfl + 16-lane softmax.
// Coalesced col reads, uint4 rowse prologue, CSR self-edge, zero-row tails
// all kept from R16. GEMMs/partition/swizzle unchanged.
// ---------------------------------------------------------------------------

#define BSHIFT 9
#define BSIZE  512            // nodes per bucket; NB = ceil(N/512) = 196 < 256
#define CAPSHIFT 14           // 16384 edge slots per bucket (mean fill ~8.7K)
#define P2_T   1024
#define P2_I   16             // edges staged per thread in partition pass

using half8  = __attribute__((ext_vector_type(8))) _Float16;
using f32x4  = __attribute__((ext_vector_type(4))) float;

__device__ __forceinline__ unsigned char f32_to_fp8(float v) {
    int p = __builtin_amdgcn_cvt_pk_fp8_f32(v, v, 0, false);
    return (unsigned char)(p & 0xff);
}

// accumulate 4 fp8 (one dword) into acc[0..3]
__device__ __forceinline__ void fp8x4_acc(unsigned int v, float* acc) {
    auto f0 = __builtin_amdgcn_cvt_pk_f32_fp8((int)v, false);
    auto f1 = __builtin_amdgcn_cvt_pk_f32_fp8((int)v, true);
    acc[0] += f0[0]; acc[1] += f0[1]; acc[2] += f1[0]; acc[3] += f1[1];
}

// --- partition edges into fixed-capacity dst-buckets, packed src|dstLocal ---
__global__ __launch_bounds__(1024) void partition_kernel(const int* __restrict__ src,
                                                         const int* __restrict__ dst,
                                                         unsigned int* __restrict__ bucket_fill,
                                                         unsigned int* __restrict__ ebuf,
                                                         int E, int NB) {
    __shared__ unsigned int hist[256];
    __shared__ unsigned int cur[256];
    int t = threadIdx.x;
    if (t < 256) hist[t] = 0u;
    __syncthreads();
    size_t base = (size_t)blockIdx.x * (P2_T * P2_I);
    int sv[P2_I], dv[P2_I];
#pragma unroll
    for (int i = 0; i < P2_I; ++i) {
        size_t idx = base + (size_t)i * P2_T + t;
        if (idx < (size_t)E) {
            sv[i] = src[idx];
            dv[i] = dst[idx];
            atomicAdd(&hist[dv[i] >> BSHIFT], 1u);
        } else dv[i] = -1;
    }
    __syncthreads();
    if (t < NB && hist[t] > 0u)
        cur[t] = ((unsigned int)t << CAPSHIFT) + atomicAdd(&bucket_fill[t], hist[t]);
    __syncthreads();
#pragma unroll
    for (int i = 0; i < P2_I; ++i) {
        if (dv[i] >= 0) {
            int b = dv[i] >> BSHIFT;
            unsigned int pos = atomicAdd(&cur[b], 1u);
            ebuf[pos] = (unsigned int)sv[i] | ((unsigned int)(dv[i] & (BSIZE - 1)) << 17);
        }
    }
}

// --- per-bucket CSR: self-edge injected; rowse=(start,end,dinv) per node ---
__global__ __launch_bounds__(256) void bucket_scatter2_kernel(const unsigned int* __restrict__ ebuf,
                                                              const unsigned int* __restrict__ bfill,
                                                              uint4* __restrict__ rowse,
                                                              float* __restrict__ dinv,
                                                              int* __restrict__ col, int N) {
    __shared__ unsigned int ldeg[BSIZE];
    __shared__ unsigned int lcur[BSIZE];
    __shared__ unsigned int part[256];
    int b = blockIdx.x, t = threadIdx.x;
    int node0 = b << BSHIFT;
    int nn = min(BSIZE, N - node0);
    ldeg[t]       = (t < nn) ? 1u : 0u;          // self edge pre-counted
    ldeg[t + 256] = (t + 256 < nn) ? 1u : 0u;
    __syncthreads();
    unsigned int e0 = (unsigned int)b << CAPSHIFT;
    unsigned int e1 = e0 + bfill[b];
    for (unsigned int e = e0 + t; e < e1; e += 256)
        atomicAdd(&ldeg[ebuf[e] >> 17], 1u);
    __syncthreads();
    unsigned int a0 = ldeg[2 * t], a1 = ldeg[2 * t + 1];
    part[t] = a0 + a1;
    __syncthreads();
    for (int off = 1; off < 256; off <<= 1) {
        unsigned int u = part[t];
        if (t >= off) u += part[t - off];
        __syncthreads();
        part[t] = u;
        __syncthreads();
    }
    unsigned int ex = part[t] - (a0 + a1);
    lcur[2 * t]     = e0 + ex;
    lcur[2 * t + 1] = e0 + ex + a0;
    __syncthreads();
    for (int i = t; i < nn; i += 256) {          // write self edge first
        unsigned int p = lcur[i];
        col[p] = node0 + i;
        lcur[i] = p + 1u;
    }
    __syncthreads();
    for (unsigned int e = e0 + t; e < e1; e += 256) {
        unsigned int p = ebuf[e];
        unsigned int pos = atomicAdd(&lcur[p >> 17], 1u);
        col[pos] = (int)(p & 0x1FFFFu);
    }
    __syncthreads();
    for (int i = t; i < nn; i += 256) {
        unsigned int cnt = ldeg[i];              // deg + 1 (self)
        unsigned int ev = lcur[i];               // row end
        float dv = rsqrtf((float)cnt);
        rowse[node0 + i] = make_uint4(ev - cnt, ev, __float_as_uint(dv), 0u);
        dinv[node0 + i] = dv;
    }
}

// --- swizzle W1 (128x128) and W2 (128x64) into MFMA B-fragment order -------
__global__ __launch_bounds__(256) void swizzle_w_kernel(const float* __restrict__ W1,
                                                        const float* __restrict__ W2,
                                                        __half* __restrict__ w1s,
                                                        __half* __restrict__ w2s) {
    int t = blockIdx.x * 256 + threadIdx.x;
    int stride = gridDim.x * 256;
    for (int i = t; i < 8 * 4 * 64 * 8; i += stride) {   // W1: 8 col-tiles
        int j = i & 7, l = (i >> 3) & 63, s = (i >> 9) & 3, c = i >> 11;
        int k = ((l >> 4) * 8) + j + 32 * s;
        int nn = 16 * c + (l & 15);
        w1s[i] = __float2half(W1[k * 128 + nn]);
    }
    for (int i = t; i < 4 * 4 * 64 * 8; i += stride) {   // W2: 4 col-tiles
        int j = i & 7, l = (i >> 3) & 63, s = (i >> 9) & 3, c = i >> 11;
        int k = ((l >> 4) * 8) + j + 32 * s;
        int nn = 16 * c + (l & 15);
        w2s[i] = __float2half(W2[k * 64 + nn]);
    }
}

// --- GEMM1 (MFMA): Y8[r,128] = fp8( dinv[r] * (X[r,128] @ W1) ), X fp32 ----
__global__ __launch_bounds__(256) void gemm1_mfma_kernel(const float* __restrict__ X,
                                                         const __half* __restrict__ w1s,
                                                         const float* __restrict__ dinv,
                                                         unsigned char* __restrict__ Y8, int n) {
    int t = threadIdx.x;
    int wave = t >> 6, lane = t & 63;
    int quad = lane >> 4, m = lane & 15;
    int rowbase = blockIdx.x * 64 + wave * 16;
    int arow = rowbase + m;
    bool aok = arow < n;
    const float* xr = X + (size_t)arow * 128 + quad * 8;

    half8 afrag[4];
#pragma unroll
    for (int s = 0; s < 4; ++s) {
        float4 p0 = make_float4(0.f, 0.f, 0.f, 0.f), p1 = p0;
        if (aok) {
            p0 = *(const float4*)(xr + s * 32);
            p1 = *(const float4*)(xr + s * 32 + 4);
        }
        afrag[s][0] = (_Float16)p0.x; afrag[s][1] = (_Float16)p0.y;
        afrag[s][2] = (_Float16)p0.z; afrag[s][3] = (_Float16)p0.w;
        afrag[s][4] = (_Float16)p1.x; afrag[s][5] = (_Float16)p1.y;
        afrag[s][6] = (_Float16)p1.z; afrag[s][7] = (_Float16)p1.w;
    }

    const half8* bp = (const half8*)w1s;
    f32x4 acc[8];
#pragma unroll
    for (int c = 0; c < 8; ++c) acc[c] = (f32x4){0.f, 0.f, 0.f, 0.f};
#pragma unroll
    for (int c = 0; c < 8; ++c)
#pragma unroll
        for (int s = 0; s < 4; ++s)
            acc[c] = __builtin_amdgcn_mfma_f32_16x16x32_f16(afrag[s], bp[(c * 4 + s) * 64 + lane], acc[c], 0, 0, 0);

#pragma unroll
    for (int i = 0; i < 4; ++i) {
        int row = rowbase + quad * 4 + i;
        if (row < n) {
            float w = dinv[row];
            unsigned char* yr = Y8 + (size_t)row * 128 + m;
#pragma unroll
            for (int c = 0; c < 8; ++c) yr[c * 16] = f32_to_fp8(acc[c][i] * w);
        }
    }
}

// --- GEMM2 (MFMA): Y8[r,64] = fp8( dinv[r] * (Xh[r,128] @ W2) ), X fp16 ----
__global__ __launch_bounds__(256) void gemm2_mfma_kernel(const __half* __restrict__ X,
                                                         const __half* __restrict__ w2s,
                                                         const float* __restrict__ dinv,
                                                         unsigned char* __restrict__ Y8, int n) {
    int t = threadIdx.x;
    int wave = t >> 6, lane = t & 63;
    int quad = lane >> 4, m = lane & 15;
    int rowbase = blockIdx.x * 64 + wave * 16;
    int arow = rowbase + m;
    bool aok = arow < n;
    const __half* xr = X + (size_t)arow * 128 + quad * 8;

    half8 afrag[4];
#pragma unroll
    for (int s = 0; s < 4; ++s) {
        if (aok) afrag[s] = *(const half8*)(xr + s * 32);
        else     afrag[s] = (half8){0, 0, 0, 0, 0, 0, 0, 0};
    }

    const half8* bp = (const half8*)w2s;
    f32x4 acc[4];
#pragma unroll
    for (int c = 0; c < 4; ++c) acc[c] = (f32x4){0.f, 0.f, 0.f, 0.f};
#pragma unroll
    for (int c = 0; c < 4; ++c)
#pragma unroll
        for (int s = 0; s < 4; ++s)
            acc[c] = __builtin_amdgcn_mfma_f32_16x16x32_f16(afrag[s], bp[(c * 4 + s) * 64 + lane], acc[c], 0, 0, 0);

#pragma unroll
    for (int i = 0; i < 4; ++i) {
        int row = rowbase + quad * 4 + i;
        if (row < n) {
            float w = dinv[row];
            unsigned char* yr = Y8 + (size_t)row * 64 + m;
#pragma unroll
            for (int c = 0; c < 4; ++c) yr[c * 16] = f32_to_fp8(acc[c][i] * w);
        }
    }
}

// --- pull layer 1: H[d] = relu(dinv[d]*(sum T'[col]) + b1), F=128 ----------
// R17: 1 node/wave. lane=(g=lane>>5 edge-parity, c=lane&31 feature-quad).
// One dword gather covers 2 rows; 4 gathers = 8 edges/iter. acc[4]; epilogue
// is 4x shfl_xor(32). col[] reads coalesced (2 adjacent ints). Zero-row pad.
__global__ __launch_bounds__(256) void pull_agg1_kernel(const unsigned char* __restrict__ T8,
                                                        const int* __restrict__ col,
                                                        const uint4* __restrict__ rowse,
                                                        const float* __restrict__ b1,
                                                        __half* __restrict__ H, int N) {
    int node = blockIdx.x * 4 + (threadIdx.x >> 6);
    if (node >= N) return;
    int lane = threadIdx.x & 63;
    int g = lane >> 5, c = lane & 31;
    unsigned int boff = (unsigned int)c << 2;      // 4B per lane, 128B per row

    uint4 rs = rowse[node];
    unsigned int e   = __builtin_amdgcn_readfirstlane(rs.x);
    unsigned int end = __builtin_amdgcn_readfirstlane(rs.y);
    float dv = __uint_as_float(__builtin_amdgcn_readfirstlane(rs.z));
    unsigned int ZR = (unsigned int)N;             // zero row

    float acc[4];
#pragma unroll
    for (int j = 0; j < 4; ++j) acc[j] = 0.f;

    while (e < end) {                              // 8 edges/iter (4 gathers)
#pragma unroll
        for (int k = 0; k < 4; ++k) {
            unsigned int pos = e + 2u * k + (unsigned int)g;
            unsigned int cc = (unsigned int)col[pos < end ? pos : end - 1u];
            unsigned int idx = (pos < end) ? cc : ZR;
            unsigned int v = *(const unsigned int*)(T8 + idx * 128u + boff);
            fp8x4_acc(v, acc);
        }
        e += 8u;
    }

#pragma unroll
    for (int j = 0; j < 4; ++j) acc[j] += __shfl_xor(acc[j], 32);

    if (g == 0) {                                  // 32 lanes x 8B = 256B row
        float4 bb = ((const float4*)b1)[c];
        __half2 o0 = __floats2half2_rn(fmaxf(fmaf(dv, acc[0], bb.x), 0.f),
                                       fmaxf(fmaf(dv, acc[1], bb.y), 0.f));
        __half2 o1 = __floats2half2_rn(fmaxf(fmaf(dv, acc[2], bb.z), 0.f),
                                       fmaxf(fmaf(dv, acc[3], bb.w), 0.f));
        uint2 st;
        st.x = *(unsigned int*)&o0;
        st.y = *(unsigned int*)&o1;
        ((uint2*)H)[(size_t)node * 32 + c] = st;
    }
}

// --- pull layer 2 + logsoftmax: out[d] = lsm(dinv[d]*sum + b2), F=64 -------
// R17: 1 node/wave. lane=(g=lane>>4 edge-slot, c=lane&15 feature-quad).
// One dword gather covers 4 rows; 2 gathers = 8 edges/iter. acc[4]; epilogue
// 8 shfl + softmax within the 16-lane feature space. Zero-row pad.
__global__ __launch_bounds__(256) void pull_agg2_kernel(const unsigned char* __restrict__ T8,
                                                        const int* __restrict__ col,
                                                        const uint4* __restrict__ rowse,
                                                        const float* __restrict__ b2,
                                                        float* __restrict__ OUT, int N) {
    int node = blockIdx.x * 4 + (threadIdx.x >> 6);
    if (node >= N) return;
    int lane = threadIdx.x & 63;
    int g = lane >> 4, c = lane & 15;
    unsigned int boff = (unsigned int)c << 2;      // 4B per lane, 64B per row

    uint4 rs = rowse[node];
    unsigned int e   = __builtin_amdgcn_readfirstlane(rs.x);
    unsigned int end = __builtin_amdgcn_readfirstlane(rs.y);
    float dv = __uint_as_float(__builtin_amdgcn_readfirstlane(rs.z));
    unsigned int ZR = (unsigned int)N;

    float acc[4];
#pragma unroll
    for (int j = 0; j < 4; ++j) acc[j] = 0.f;

    while (e < end) {                              // 8 edges/iter (2 gathers)
#pragma unroll
        for (int k = 0; k < 2; ++k) {
            unsigned int pos = e + 4u * k + (unsigned int)g;
            unsigned int cc = (unsigned int)col[pos < end ? pos : end - 1u];
            unsigned int idx = (pos < end) ? cc : ZR;
            unsigned int v = *(const unsigned int*)(T8 + idx * 64u + boff);
            fp8x4_acc(v, acc);
        }
        e += 8u;
    }

#pragma unroll
    for (int j = 0; j < 4; ++j) {                  // reduce over g (bits 4,5)
        acc[j] += __shfl_xor(acc[j], 16);
        acc[j] += __shfl_xor(acc[j], 32);
    }

    // every lane now holds totals for features c*4..c*4+3
    float4 bb = ((const float4*)b2)[c];
    float v0 = fmaf(dv, acc[0], bb.x);
    float v1 = fmaf(dv, acc[1], bb.y);
    float v2 = fmaf(dv, acc[2], bb.z);
    float v3 = fmaf(dv, acc[3], bb.w);
    float m = fmaxf(fmaxf(v0, v1), fmaxf(v2, v3));
#pragma unroll
    for (int off = 1; off < 16; off <<= 1) m = fmaxf(m, __shfl_xor(m, off));
    float sum = __expf(v0 - m) + __expf(v1 - m) + __expf(v2 - m) + __expf(v3 - m);
#pragma unroll
    for (int off = 1; off < 16; off <<= 1) sum += __shfl_xor(sum, off);
    float ls = m + logf(sum);

    if (g == 0)                                    // 16 lanes x 16B = 256B row
        ((float4*)OUT)[(size_t)node * 16 + c] =
            make_float4(v0 - ls, v1 - ls, v2 - ls, v3 - ls);
}

extern "C" void kernel_launch(void* const* d_in, const int* in_sizes, int n_in,
                              void* d_out, int out_size, void* d_ws, size_t ws_size,
                              hipStream_t stream) {
    const float* x   = (const float*)d_in[0];
    const int*   ei  = (const int*)d_in[1];   // int32 per harness contract
    const float* W1  = (const float*)d_in[2];
    const float* b1  = (const float*)d_in[3];
    const float* W2  = (const float*)d_in[4];
    const float* b2  = (const float*)d_in[5];
    float*       out = (float*)d_out;

    const int N = in_sizes[0] / 128;      // 100000
    const int E = in_sizes[1] / 2;        // 1600000
    const int* src = ei;
    const int* dst = ei + E;
    const int NB = (N + BSIZE - 1) >> BSHIFT;   // dst buckets (196 <= 256)
    const size_t CAPTOT = (size_t)NB << CAPSHIFT;

    // workspace layout
    char* ws = (char*)d_ws;
    size_t off = 0;
    auto alloc = [&](size_t bytes) { void* p = ws + off; off = (off + bytes + 255) & ~(size_t)255; return p; };
    float*        dinv   = (float*)alloc((size_t)N * 4);
    uint4*        rowse  = (uint4*)alloc((size_t)N * 16);       // start,end,dinv
    unsigned int* bf     = (unsigned int*)alloc(256 * 4);       // bucket_fill
    __half*       w1s    = (__half*)alloc(128 * 128 * 2);       // swizzled W1
    __half*       w2s    = (__half*)alloc(128 * 64 * 2);        // swizzled W2
    int*          col    = (int*)alloc(CAPTOT * 4);             // CAP-strided
    unsigned char* A1    = (unsigned char*)alloc((size_t)(N + 1) * 128); // T1' fp8 (+zero row)
    unsigned char* A2    = (unsigned char*)alloc((size_t)(N + 1) * 64);  // T2' fp8 (+zero row)
    __half*       B      = (__half*)alloc((size_t)N * 128 * 2);          // h fp16
    unsigned int* ebuf   = (unsigned int*)alloc(CAPTOT * 4);

    // 0. zero bucket fills + the two zero-pad rows
    hipMemsetAsync(bf, 0, 256 * 4, stream);
    hipMemsetAsync(A1 + (size_t)N * 128, 0, 128, stream);
    hipMemsetAsync(A2 + (size_t)N * 64, 0, 64, stream);

    // 1. CSR build: partition into fixed-capacity buckets -> per-bucket scatter
    partition_kernel<<<(E + P2_T * P2_I - 1) / (P2_T * P2_I), P2_T, 0, stream>>>(src, dst, bf, ebuf, E, NB);
    bucket_scatter2_kernel<<<NB, 256, 0, stream>>>(ebuf, bf, rowse, dinv, col, N);

    // 1b. swizzle weights into MFMA fragment order
    swizzle_w_kernel<<<64, 256, 0, stream>>>(W1, W2, w1s, w2s);

    // 2. T1' = fp8(dinv * (x @ W1)) [MFMA];  h = relu(dinv*(pull) + b1)
    gemm1_mfma_kernel<<<(N + 63) / 64, 256, 0, stream>>>(x, w1s, dinv, A1, N);
    pull_agg1_kernel<<<(N + 3) / 4, 256, 0, stream>>>(A1, col, rowse, b1, B, N);

    // 3. T2' = fp8(dinv * (h @ W2)) [MFMA];  out = logsoftmax(dinv*(pull) + b2)
    gemm2_mfma_kernel<<<(N + 63) / 64, 256, 0, stream>>>(B, w2s, dinv, A2, N);
    pull_agg2_kernel<<<(N + 3) / 4, 256, 0, stream>>>(A2, col, rowse, b2, out, N);
}

// Round 12
// 264.893 us; speedup vs baseline: 1.1379x; 1.1199x over previous
//
#include <hip/hip_runtime.h>
#include <hip/hip_fp16.h>

// ---------------------------------------------------------------------------
// GCN 2-layer forward:  out = log_softmax( A_hat * relu(A_hat * (x W1) + b1) W2 + b2 )
// A_hat = D^-1/2 (A + I) D^-1/2, deg on dst. Edge index arrives as int32.
//
// R18: composite of verified-best pieces + col-prefetch pipeline.
//   Pulls: R14's exact structure (best measured: agg1 54.7us) -- 1 row/instr
//   ushort gathers, 2 nodes/wave paired (agg1) / node-per-half (agg2) --
//   plus software-pipelined col loads: next burst's indices issue while the
//   current burst's gathers are consumed (hides the ~500cy col leg).
//   CSR: fixed-capacity buckets (R15, verified) -- hist+scan deleted.
//   swizzle_w: 64 blocks. GEMMs: fp16 MFMA with fp8 e4m3 output (R14).
// ---------------------------------------------------------------------------

#define BSHIFT 9
#define BSIZE  512            // nodes per bucket; NB = ceil(N/512) = 196 < 256
#define CAPSHIFT 14           // 16384 edge slots per bucket (mean fill ~8.2K)
#define P2_T   1024
#define P2_I   16             // edges staged per thread in partition pass

using half8  = __attribute__((ext_vector_type(8))) _Float16;
using f32x4  = __attribute__((ext_vector_type(4))) float;

__device__ __forceinline__ unsigned char f32_to_fp8(float v) {
    int p = __builtin_amdgcn_cvt_pk_fp8_f32(v, v, 0, false);
    return (unsigned char)(p & 0xff);
}

// --- partition edges into fixed-capacity dst-buckets, packed src|dstLocal ---
__global__ __launch_bounds__(1024) void partition_kernel(const int* __restrict__ src,
                                                         const int* __restrict__ dst,
                                                         unsigned int* __restrict__ bucket_fill,
                                                         unsigned int* __restrict__ ebuf,
                                                         int E, int NB) {
    __shared__ unsigned int hist[256];
    __shared__ unsigned int cur[256];
    int t = threadIdx.x;
    if (t < 256) hist[t] = 0u;
    __syncthreads();
    size_t base = (size_t)blockIdx.x * (P2_T * P2_I);
    int sv[P2_I], dv[P2_I];
#pragma unroll
    for (int i = 0; i < P2_I; ++i) {
        size_t idx = base + (size_t)i * P2_T + t;
        if (idx < (size_t)E) {
            sv[i] = src[idx];
            dv[i] = dst[idx];
            atomicAdd(&hist[dv[i] >> BSHIFT], 1u);
        } else dv[i] = -1;
    }
    __syncthreads();
    if (t < NB && hist[t] > 0u)
        cur[t] = ((unsigned int)t << CAPSHIFT) + atomicAdd(&bucket_fill[t], hist[t]);
    __syncthreads();
#pragma unroll
    for (int i = 0; i < P2_I; ++i) {
        if (dv[i] >= 0) {
            int b = dv[i] >> BSHIFT;
            unsigned int pos = atomicAdd(&cur[b], 1u);
            ebuf[pos] = (unsigned int)sv[i] | ((unsigned int)(dv[i] & (BSIZE - 1)) << 17);
        }
    }
}

// --- per-bucket deg/dinv/rowptr in LDS + scatter; cursor=rowend ------------
__global__ __launch_bounds__(256) void bucket_scatter2_kernel(const unsigned int* __restrict__ ebuf,
                                                              const unsigned int* __restrict__ bfill,
                                                              unsigned int* __restrict__ cursor,
                                                              unsigned int* __restrict__ deg,
                                                              float* __restrict__ dinv,
                                                              int* __restrict__ col, int N) {
    __shared__ unsigned int ldeg[BSIZE];
    __shared__ unsigned int lcur[BSIZE];
    __shared__ unsigned int part[256];
    int b = blockIdx.x, t = threadIdx.x;
    int node0 = b << BSHIFT;
    int nn = min(BSIZE, N - node0);
    ldeg[t] = 0u;
    ldeg[t + 256] = 0u;
    __syncthreads();
    unsigned int e0 = (unsigned int)b << CAPSHIFT;
    unsigned int e1 = e0 + bfill[b];
    for (unsigned int e = e0 + t; e < e1; e += 256)
        atomicAdd(&ldeg[ebuf[e] >> 17], 1u);
    __syncthreads();
    unsigned int a0 = ldeg[2 * t], a1 = ldeg[2 * t + 1];
    part[t] = a0 + a1;
    __syncthreads();
    for (int off = 1; off < 256; off <<= 1) {
        unsigned int u = part[t];
        if (t >= off) u += part[t - off];
        __syncthreads();
        part[t] = u;
        __syncthreads();
    }
    unsigned int ex = part[t] - (a0 + a1);
    lcur[2 * t]     = e0 + ex;
    lcur[2 * t + 1] = e0 + ex + a0;
    __syncthreads();
    for (unsigned int e = e0 + t; e < e1; e += 256) {
        unsigned int p = ebuf[e];
        unsigned int pos = atomicAdd(&lcur[p >> 17], 1u);
        col[pos] = (int)(p & 0x1FFFFu);
    }
    __syncthreads();
    for (int i = t; i < nn; i += 256) {
        unsigned int d = ldeg[i];
        deg[node0 + i] = d;
        dinv[node0 + i] = rsqrtf((float)(d + 1u));
        cursor[node0 + i] = lcur[i];
    }
}

// --- swizzle W1 (128x128) and W2 (128x64) into MFMA B-fragment order -------
__global__ __launch_bounds__(256) void swizzle_w_kernel(const float* __restrict__ W1,
                                                        const float* __restrict__ W2,
                                                        __half* __restrict__ w1s,
                                                        __half* __restrict__ w2s) {
    int t = blockIdx.x * 256 + threadIdx.x;
    int stride = gridDim.x * 256;
    for (int i = t; i < 8 * 4 * 64 * 8; i += stride) {   // W1: 8 col-tiles
        int j = i & 7, l = (i >> 3) & 63, s = (i >> 9) & 3, c = i >> 11;
        int k = ((l >> 4) * 8) + j + 32 * s;
        int nn = 16 * c + (l & 15);
        w1s[i] = __float2half(W1[k * 128 + nn]);
    }
    for (int i = t; i < 4 * 4 * 64 * 8; i += stride) {   // W2: 4 col-tiles
        int j = i & 7, l = (i >> 3) & 63, s = (i >> 9) & 3, c = i >> 11;
        int k = ((l >> 4) * 8) + j + 32 * s;
        int nn = 16 * c + (l & 15);
        w2s[i] = __float2half(W2[k * 64 + nn]);
    }
}

// --- GEMM1 (MFMA): Y8[r,128] = fp8( dinv[r] * (X[r,128] @ W1) ), X fp32 ----
__global__ __launch_bounds__(256) void gemm1_mfma_kernel(const float* __restrict__ X,
                                                         const __half* __restrict__ w1s,
                                                         const float* __restrict__ dinv,
                                                         unsigned char* __restrict__ Y8, int n) {
    int t = threadIdx.x;
    int wave = t >> 6, lane = t & 63;
    int quad = lane >> 4, m = lane & 15;
    int rowbase = blockIdx.x * 64 + wave * 16;
    int arow = rowbase + m;
    bool aok = arow < n;
    const float* xr = X + (size_t)arow * 128 + quad * 8;

    half8 afrag[4];
#pragma unroll
    for (int s = 0; s < 4; ++s) {
        float4 p0 = make_float4(0.f, 0.f, 0.f, 0.f), p1 = p0;
        if (aok) {
            p0 = *(const float4*)(xr + s * 32);
            p1 = *(const float4*)(xr + s * 32 + 4);
        }
        afrag[s][0] = (_Float16)p0.x; afrag[s][1] = (_Float16)p0.y;
        afrag[s][2] = (_Float16)p0.z; afrag[s][3] = (_Float16)p0.w;
        afrag[s][4] = (_Float16)p1.x; afrag[s][5] = (_Float16)p1.y;
        afrag[s][6] = (_Float16)p1.z; afrag[s][7] = (_Float16)p1.w;
    }

    const half8* bp = (const half8*)w1s;
    f32x4 acc[8];
#pragma unroll
    for (int c = 0; c < 8; ++c) acc[c] = (f32x4){0.f, 0.f, 0.f, 0.f};
#pragma unroll
    for (int c = 0; c < 8; ++c)
#pragma unroll
        for (int s = 0; s < 4; ++s)
            acc[c] = __builtin_amdgcn_mfma_f32_16x16x32_f16(afrag[s], bp[(c * 4 + s) * 64 + lane], acc[c], 0, 0, 0);

#pragma unroll
    for (int i = 0; i < 4; ++i) {
        int row = rowbase + quad * 4 + i;
        if (row < n) {
            float w = dinv[row];
            unsigned char* yr = Y8 + (size_t)row * 128 + m;
#pragma unroll
            for (int c = 0; c < 8; ++c) yr[c * 16] = f32_to_fp8(acc[c][i] * w);
        }
    }
}

// --- GEMM2 (MFMA): Y8[r,64] = fp8( dinv[r] * (Xh[r,128] @ W2) ), X fp16 ----
__global__ __launch_bounds__(256) void gemm2_mfma_kernel(const __half* __restrict__ X,
                                                         const __half* __restrict__ w2s,
                                                         const float* __restrict__ dinv,
                                                         unsigned char* __restrict__ Y8, int n) {
    int t = threadIdx.x;
    int wave = t >> 6, lane = t & 63;
    int quad = lane >> 4, m = lane & 15;
    int rowbase = blockIdx.x * 64 + wave * 16;
    int arow = rowbase + m;
    bool aok = arow < n;
    const __half* xr = X + (size_t)arow * 128 + quad * 8;

    half8 afrag[4];
#pragma unroll
    for (int s = 0; s < 4; ++s) {
        if (aok) afrag[s] = *(const half8*)(xr + s * 32);
        else     afrag[s] = (half8){0, 0, 0, 0, 0, 0, 0, 0};
    }

    const half8* bp = (const half8*)w2s;
    f32x4 acc[4];
#pragma unroll
    for (int c = 0; c < 4; ++c) acc[c] = (f32x4){0.f, 0.f, 0.f, 0.f};
#pragma unroll
    for (int c = 0; c < 4; ++c)
#pragma unroll
        for (int s = 0; s < 4; ++s)
            acc[c] = __builtin_amdgcn_mfma_f32_16x16x32_f16(afrag[s], bp[(c * 4 + s) * 64 + lane], acc[c], 0, 0, 0);

#pragma unroll
    for (int i = 0; i < 4; ++i) {
        int row = rowbase + quad * 4 + i;
        if (row < n) {
            float w = dinv[row];
            unsigned char* yr = Y8 + (size_t)row * 64 + m;
#pragma unroll
            for (int c = 0; c < 4; ++c) yr[c * 16] = f32_to_fp8(acc[c][i] * w);
        }
    }
}

// --- pull layer 1: H[d] = relu(dinv[d]*(T'[d] + sum T'[col]) + b1), F=128 --
// R18 = R14 structure + col-prefetch pipeline. T' fp8 (128B rows).
// 2 nodes/wave, paired 8-bursts; next burst's col indices load while the
// current burst's gathers are consumed.
__global__ __launch_bounds__(256) void pull_agg1_kernel(const unsigned char* __restrict__ T8,
                                                        const int* __restrict__ col,
                                                        const unsigned int* __restrict__ cursor,
                                                        const unsigned int* __restrict__ deg,
                                                        const float* __restrict__ dinv,
                                                        const float* __restrict__ b1,
                                                        __half* __restrict__ H, int N) {
    int pair = blockIdx.x * 4 + (threadIdx.x >> 6);
    int nodeA = pair * 2;
    if (nodeA >= N) return;
    int nodeB = nodeA + 1;
    bool hasB = nodeB < N;
    int lane = threadIdx.x & 63;
    unsigned int boff = (unsigned int)lane << 1;

    unsigned int endA = cursor[nodeA];
    unsigned int eA = endA - deg[nodeA];
    endA = __builtin_amdgcn_readfirstlane(endA);
    eA   = __builtin_amdgcn_readfirstlane(eA);
    unsigned int endB = 0u, eB = 0u;
    if (hasB) { endB = cursor[nodeB]; eB = endB - deg[nodeB]; }
    endB = __builtin_amdgcn_readfirstlane(endB);
    eB   = __builtin_amdgcn_readfirstlane(eB);

    unsigned short uSA = *(const unsigned short*)(T8 + (unsigned int)nodeA * 128u + boff);
    auto fSA = __builtin_amdgcn_cvt_pk_f32_fp8((int)uSA, false);
    float a0 = fSA[0], a1 = fSA[1];
    float c0 = 0.f, c1 = 0.f;
    if (hasB) {
        unsigned short uSB = *(const unsigned short*)(T8 + (unsigned int)nodeB * 128u + boff);
        auto fSB = __builtin_amdgcn_cvt_pk_f32_fp8((int)uSB, false);
        c0 = fSB[0]; c1 = fSB[1];
    }

    // paired 8-bursts with col prefetch: cols for burst i+1 issue while
    // burst i's gathers are consumed.
    unsigned int sA[8], sB[8];
    bool ok = (eA + 8 <= endA) && (eB + 8 <= endB);
    if (ok) {
#pragma unroll
        for (int k = 0; k < 8; ++k) sA[k] = (unsigned int)col[eA + k];
#pragma unroll
        for (int k = 0; k < 8; ++k) sB[k] = (unsigned int)col[eB + k];
    }
    while (ok) {
        unsigned short vA[8], vB[8];
#pragma unroll
        for (int k = 0; k < 8; ++k) vA[k] = *(const unsigned short*)(T8 + sA[k] * 128u + boff);
#pragma unroll
        for (int k = 0; k < 8; ++k) vB[k] = *(const unsigned short*)(T8 + sB[k] * 128u + boff);
        eA += 8; eB += 8;
        bool nok = (eA + 8 <= endA) && (eB + 8 <= endB);
        unsigned int nA[8], nB[8];
        if (nok) {
#pragma unroll
            for (int k = 0; k < 8; ++k) nA[k] = (unsigned int)col[eA + k];
#pragma unroll
            for (int k = 0; k < 8; ++k) nB[k] = (unsigned int)col[eB + k];
        }
#pragma unroll
        for (int k = 0; k < 8; ++k) {
            auto f = __builtin_amdgcn_cvt_pk_f32_fp8((int)vA[k], false);
            a0 += f[0]; a1 += f[1];
        }
#pragma unroll
        for (int k = 0; k < 8; ++k) {
            auto f = __builtin_amdgcn_cvt_pk_f32_fp8((int)vB[k], false);
            c0 += f[0]; c1 += f[1];
        }
        if (nok) {
#pragma unroll
            for (int k = 0; k < 8; ++k) { sA[k] = nA[k]; sB[k] = nB[k]; }
        }
        ok = nok;
    }
    // drain A
    for (; eA + 8 <= endA; eA += 8) {
        unsigned int s[8];
#pragma unroll
        for (int k = 0; k < 8; ++k) s[k] = (unsigned int)col[eA + k];
        unsigned short v[8];
#pragma unroll
        for (int k = 0; k < 8; ++k) v[k] = *(const unsigned short*)(T8 + s[k] * 128u + boff);
#pragma unroll
        for (int k = 0; k < 8; ++k) {
            auto f = __builtin_amdgcn_cvt_pk_f32_fp8((int)v[k], false);
            a0 += f[0]; a1 += f[1];
        }
    }
    for (; eA < endA; ++eA) {
        unsigned short u = *(const unsigned short*)(T8 + (unsigned int)col[eA] * 128u + boff);
        auto f = __builtin_amdgcn_cvt_pk_f32_fp8((int)u, false);
        a0 += f[0]; a1 += f[1];
    }
    // drain B
    for (; eB + 8 <= endB; eB += 8) {
        unsigned int s[8];
#pragma unroll
        for (int k = 0; k < 8; ++k) s[k] = (unsigned int)col[eB + k];
        unsigned short v[8];
#pragma unroll
        for (int k = 0; k < 8; ++k) v[k] = *(const unsigned short*)(T8 + s[k] * 128u + boff);
#pragma unroll
        for (int k = 0; k < 8; ++k) {
            auto f = __builtin_amdgcn_cvt_pk_f32_fp8((int)v[k], false);
            c0 += f[0]; c1 += f[1];
        }
    }
    for (; eB < endB; ++eB) {
        unsigned short u = *(const unsigned short*)(T8 + (unsigned int)col[eB] * 128u + boff);
        auto f = __builtin_amdgcn_cvt_pk_f32_fp8((int)u, false);
        c0 += f[0]; c1 += f[1];
    }

    float2 b = ((const float2*)b1)[lane];
    float wA = dinv[nodeA];
    float hx = fmaxf(fmaf(wA, a0, b.x), 0.f);
    float hy = fmaxf(fmaf(wA, a1, b.y), 0.f);
    ((__half2*)H)[(unsigned int)nodeA * 64u + lane] = __floats2half2_rn(hx, hy);
    if (hasB) {
        float wB = dinv[nodeB];
        float gx = fmaxf(fmaf(wB, c0, b.x), 0.f);
        float gy = fmaxf(fmaf(wB, c1, b.y), 0.f);
        ((__half2*)H)[(unsigned int)nodeB * 64u + lane] = __floats2half2_rn(gx, gy);
    }
}

// --- pull layer 2 + logsoftmax: out[d] = lsm(dinv[d]*sum + b2), F=64 -------
// R18 = R14 structure + col prefetch. T2' fp8 (64B rows). Each 32-lane half
// owns one node end-to-end.
__global__ __launch_bounds__(256) void pull_agg2_kernel(const unsigned char* __restrict__ T8,
                                                        const int* __restrict__ col,
                                                        const unsigned int* __restrict__ cursor,
                                                        const unsigned int* __restrict__ deg,
                                                        const float* __restrict__ dinv,
                                                        const float* __restrict__ b2,
                                                        float* __restrict__ OUT, int N) {
    int node = blockIdx.x * 8 + (threadIdx.x >> 5);     // half-id within block
    if (node >= N) return;
    int c2 = threadIdx.x & 31;                          // col pair
    unsigned int boff = (unsigned int)c2 << 1;
    unsigned int end = cursor[node];
    unsigned int e = end - deg[node];

    unsigned short uS = *(const unsigned short*)(T8 + (unsigned int)node * 64u + boff);
    auto fS = __builtin_amdgcn_cvt_pk_f32_fp8((int)uS, false);
    float acc0 = fS[0], acc1 = fS[1];

    unsigned int s[8];
    bool ok = e + 8 <= end;
    if (ok) {
#pragma unroll
        for (int k = 0; k < 8; ++k) s[k] = (unsigned int)col[e + k];
    }
    while (ok) {
        unsigned short v[8];
#pragma unroll
        for (int k = 0; k < 8; ++k) v[k] = *(const unsigned short*)(T8 + s[k] * 64u + boff);
        e += 8;
        bool nok = e + 8 <= end;
        unsigned int ns[8];
        if (nok) {
#pragma unroll
            for (int k = 0; k < 8; ++k) ns[k] = (unsigned int)col[e + k];
        }
#pragma unroll
        for (int k = 0; k < 8; ++k) {
            auto f = __builtin_amdgcn_cvt_pk_f32_fp8((int)v[k], false);
            acc0 += f[0]; acc1 += f[1];
        }
        if (nok) {
#pragma unroll
            for (int k = 0; k < 8; ++k) s[k] = ns[k];
        }
        ok = nok;
    }
    for (; e < end; ++e) {
        unsigned short u = *(const unsigned short*)(T8 + (unsigned int)col[e] * 64u + boff);
        auto f = __builtin_amdgcn_cvt_pk_f32_fp8((int)u, false);
        acc0 += f[0]; acc1 += f[1];
    }

    float w = dinv[node];
    float2 b = ((const float2*)b2)[c2];
    float vx = fmaf(w, acc0, b.x);
    float vy = fmaf(w, acc1, b.y);
    float m = fmaxf(vx, vy);
#pragma unroll
    for (int off = 16; off > 0; off >>= 1) m = fmaxf(m, __shfl_xor(m, off));
    float sum = __expf(vx - m) + __expf(vy - m);
#pragma unroll
    for (int off = 16; off > 0; off >>= 1) sum += __shfl_xor(sum, off);
    float ls = m + logf(sum);
    float2 o;
    o.x = vx - ls;
    o.y = vy - ls;
    ((float2*)OUT)[(unsigned int)node * 32u + c2] = o;
}

extern "C" void kernel_launch(void* const* d_in, const int* in_sizes, int n_in,
                              void* d_out, int out_size, void* d_ws, size_t ws_size,
                              hipStream_t stream) {
    const float* x   = (const float*)d_in[0];
    const int*   ei  = (const int*)d_in[1];   // int32 per harness contract
    const float* W1  = (const float*)d_in[2];
    const float* b1  = (const float*)d_in[3];
    const float* W2  = (const float*)d_in[4];
    const float* b2  = (const float*)d_in[5];
    float*       out = (float*)d_out;

    const int N = in_sizes[0] / 128;      // 100000
    const int E = in_sizes[1] / 2;        // 1600000
    const int* src = ei;
    const int* dst = ei + E;
    const int NB = (N + BSIZE - 1) >> BSHIFT;   // dst buckets (196 <= 256)
    const size_t CAPTOT = (size_t)NB << CAPSHIFT;

    // workspace layout
    char* ws = (char*)d_ws;
    size_t off = 0;
    auto alloc = [&](size_t bytes) { void* p = ws + off; off = (off + bytes + 255) & ~(size_t)255; return p; };
    unsigned int* deg    = (unsigned int*)alloc((size_t)N * 4);
    float*        dinv   = (float*)alloc((size_t)N * 4);
    unsigned int* cursor = (unsigned int*)alloc((size_t)N * 4);
    unsigned int* bf     = (unsigned int*)alloc(256 * 4);       // bucket_fill
    __half*       w1s    = (__half*)alloc(128 * 128 * 2);       // swizzled W1
    __half*       w2s    = (__half*)alloc(128 * 64 * 2);        // swizzled W2
    int*          col    = (int*)alloc(CAPTOT * 4);             // CAP-strided
    unsigned char* A     = (unsigned char*)alloc((size_t)N * 128); // T1'/T2' fp8
    __half*       B      = (__half*)alloc((size_t)N * 128 * 2);    // h fp16
    unsigned int* ebuf   = (unsigned int*)alloc(CAPTOT * 4);

    // 1. CSR build: partition into fixed-capacity buckets -> per-bucket scatter
    hipMemsetAsync(bf, 0, 256 * 4, stream);
    partition_kernel<<<(E + P2_T * P2_I - 1) / (P2_T * P2_I), P2_T, 0, stream>>>(src, dst, bf, ebuf, E, NB);
    bucket_scatter2_kernel<<<NB, 256, 0, stream>>>(ebuf, bf, cursor, deg, dinv, col, N);
    // now cursor[i] == rowend(i); rowstart(i) = cursor[i] - deg[i]; dinv ready

    // 1b. swizzle weights into MFMA fragment order
    swizzle_w_kernel<<<64, 256, 0, stream>>>(W1, W2, w1s, w2s);

    // 2. T1' = fp8(dinv * (x @ W1)) [MFMA];  h = relu(dinv*(pull) + b1)
    gemm1_mfma_kernel<<<(N + 63) / 64, 256, 0, stream>>>(x, w1s, dinv, A, N);
    pull_agg1_kernel<<<(N + 7) / 8, 256, 0, stream>>>(A, col, cursor, deg, dinv, b1, B, N);

    // 3. T2' = fp8(dinv * (h @ W2)) [MFMA];  out = logsoftmax(dinv*(pull) + b2)
    gemm2_mfma_kernel<<<(N + 63) / 64, 256, 0, stream>>>(B, w2s, dinv, A, N);
    pull_agg2_kernel<<<(N + 7) / 8, 256, 0, stream>>>(A, col, cursor, deg, dinv, b2, out, N);
}

// Round 13
// 227.456 us; speedup vs baseline: 1.3252x; 1.1646x over previous
//
#include <hip/hip_runtime.h>
#include <hip/hip_fp16.h>

// ---------------------------------------------------------------------------
// GCN 2-layer forward:  out = log_softmax( A_hat * relu(A_hat * (x W1) + b1) W2 + b2 )
// A_hat = D^-1/2 (A + I) D^-1/2, deg on dst. Edge index arrives as int32.
//
// R19: 4 nodes per wave in both pulls (nodes-per-wave identified as the
// governing variable across R10-R18: wave lifetime is ~fixed, so throughput
// scales with nodes/wave). Quarter-wave (16 lanes) owns one node:
//   agg1: fp8 row 128B = 16 lanes x 8B; acc[8]/lane; NO cross-lane reduce.
//   agg2: fp8 row  64B = 16 lanes x 4B; acc[4]/lane; softmax within quarter.
// Finished quarters gather the L1-hot self row and cndmask to 0.
// partition: P2_I 16->4 (98 -> 391 blocks; was CU-starved).
// CSR fixed-capacity buckets, 64-block swizzle, MFMA GEMMs w/ fp8 out: R18.
// ---------------------------------------------------------------------------

#define BSHIFT 9
#define BSIZE  512            // nodes per bucket; NB = ceil(N/512) = 196 < 256
#define CAPSHIFT 14           // 16384 edge slots per bucket (mean fill ~8.2K)
#define P2_T   1024
#define P2_I   4              // edges staged per thread in partition pass

using half8  = __attribute__((ext_vector_type(8))) _Float16;
using f32x4  = __attribute__((ext_vector_type(4))) float;

__device__ __forceinline__ unsigned char f32_to_fp8(float v) {
    int p = __builtin_amdgcn_cvt_pk_fp8_f32(v, v, 0, false);
    return (unsigned char)(p & 0xff);
}

// accumulate 4 fp8 (one dword) into acc[0..3]
__device__ __forceinline__ void fp8x4_acc(unsigned int v, float* acc) {
    auto f0 = __builtin_amdgcn_cvt_pk_f32_fp8((int)v, false);
    auto f1 = __builtin_amdgcn_cvt_pk_f32_fp8((int)v, true);
    acc[0] += f0[0]; acc[1] += f0[1]; acc[2] += f1[0]; acc[3] += f1[1];
}

// --- partition edges into fixed-capacity dst-buckets, packed src|dstLocal ---
__global__ __launch_bounds__(1024) void partition_kernel(const int* __restrict__ src,
                                                         const int* __restrict__ dst,
                                                         unsigned int* __restrict__ bucket_fill,
                                                         unsigned int* __restrict__ ebuf,
                                                         int E, int NB) {
    __shared__ unsigned int hist[256];
    __shared__ unsigned int cur[256];
    int t = threadIdx.x;
    if (t < 256) hist[t] = 0u;
    __syncthreads();
    size_t base = (size_t)blockIdx.x * (P2_T * P2_I);
    int sv[P2_I], dv[P2_I];
#pragma unroll
    for (int i = 0; i < P2_I; ++i) {
        size_t idx = base + (size_t)i * P2_T + t;
        if (idx < (size_t)E) {
            sv[i] = src[idx];
            dv[i] = dst[idx];
            atomicAdd(&hist[dv[i] >> BSHIFT], 1u);
        } else dv[i] = -1;
    }
    __syncthreads();
    if (t < NB && hist[t] > 0u)
        cur[t] = ((unsigned int)t << CAPSHIFT) + atomicAdd(&bucket_fill[t], hist[t]);
    __syncthreads();
#pragma unroll
    for (int i = 0; i < P2_I; ++i) {
        if (dv[i] >= 0) {
            int b = dv[i] >> BSHIFT;
            unsigned int pos = atomicAdd(&cur[b], 1u);
            ebuf[pos] = (unsigned int)sv[i] | ((unsigned int)(dv[i] & (BSIZE - 1)) << 17);
        }
    }
}

// --- per-bucket deg/dinv/rowptr in LDS + scatter; cursor=rowend ------------
__global__ __launch_bounds__(256) void bucket_scatter2_kernel(const unsigned int* __restrict__ ebuf,
                                                              const unsigned int* __restrict__ bfill,
                                                              unsigned int* __restrict__ cursor,
                                                              unsigned int* __restrict__ deg,
                                                              float* __restrict__ dinv,
                                                              int* __restrict__ col, int N) {
    __shared__ unsigned int ldeg[BSIZE];
    __shared__ unsigned int lcur[BSIZE];
    __shared__ unsigned int part[256];
    int b = blockIdx.x, t = threadIdx.x;
    int node0 = b << BSHIFT;
    int nn = min(BSIZE, N - node0);
    ldeg[t] = 0u;
    ldeg[t + 256] = 0u;
    __syncthreads();
    unsigned int e0 = (unsigned int)b << CAPSHIFT;
    unsigned int e1 = e0 + bfill[b];
    for (unsigned int e = e0 + t; e < e1; e += 256)
        atomicAdd(&ldeg[ebuf[e] >> 17], 1u);
    __syncthreads();
    unsigned int a0 = ldeg[2 * t], a1 = ldeg[2 * t + 1];
    part[t] = a0 + a1;
    __syncthreads();
    for (int off = 1; off < 256; off <<= 1) {
        unsigned int u = part[t];
        if (t >= off) u += part[t - off];
        __syncthreads();
        part[t] = u;
        __syncthreads();
    }
    unsigned int ex = part[t] - (a0 + a1);
    lcur[2 * t]     = e0 + ex;
    lcur[2 * t + 1] = e0 + ex + a0;
    __syncthreads();
    for (unsigned int e = e0 + t; e < e1; e += 256) {
        unsigned int p = ebuf[e];
        unsigned int pos = atomicAdd(&lcur[p >> 17], 1u);
        col[pos] = (int)(p & 0x1FFFFu);
    }
    __syncthreads();
    for (int i = t; i < nn; i += 256) {
        unsigned int d = ldeg[i];
        deg[node0 + i] = d;
        dinv[node0 + i] = rsqrtf((float)(d + 1u));
        cursor[node0 + i] = lcur[i];
    }
}

// --- swizzle W1 (128x128) and W2 (128x64) into MFMA B-fragment order -------
__global__ __launch_bounds__(256) void swizzle_w_kernel(const float* __restrict__ W1,
                                                        const float* __restrict__ W2,
                                                        __half* __restrict__ w1s,
                                                        __half* __restrict__ w2s) {
    int t = blockIdx.x * 256 + threadIdx.x;
    int stride = gridDim.x * 256;
    for (int i = t; i < 8 * 4 * 64 * 8; i += stride) {   // W1: 8 col-tiles
        int j = i & 7, l = (i >> 3) & 63, s = (i >> 9) & 3, c = i >> 11;
        int k = ((l >> 4) * 8) + j + 32 * s;
        int nn = 16 * c + (l & 15);
        w1s[i] = __float2half(W1[k * 128 + nn]);
    }
    for (int i = t; i < 4 * 4 * 64 * 8; i += stride) {   // W2: 4 col-tiles
        int j = i & 7, l = (i >> 3) & 63, s = (i >> 9) & 3, c = i >> 11;
        int k = ((l >> 4) * 8) + j + 32 * s;
        int nn = 16 * c + (l & 15);
        w2s[i] = __float2half(W2[k * 64 + nn]);
    }
}

// --- GEMM1 (MFMA): Y8[r,128] = fp8( dinv[r] * (X[r,128] @ W1) ), X fp32 ----
__global__ __launch_bounds__(256) void gemm1_mfma_kernel(const float* __restrict__ X,
                                                         const __half* __restrict__ w1s,
                                                         const float* __restrict__ dinv,
                                                         unsigned char* __restrict__ Y8, int n) {
    int t = threadIdx.x;
    int wave = t >> 6, lane = t & 63;
    int quad = lane >> 4, m = lane & 15;
    int rowbase = blockIdx.x * 64 + wave * 16;
    int arow = rowbase + m;
    bool aok = arow < n;
    const float* xr = X + (size_t)arow * 128 + quad * 8;

    half8 afrag[4];
#pragma unroll
    for (int s = 0; s < 4; ++s) {
        float4 p0 = make_float4(0.f, 0.f, 0.f, 0.f), p1 = p0;
        if (aok) {
            p0 = *(const float4*)(xr + s * 32);
            p1 = *(const float4*)(xr + s * 32 + 4);
        }
        afrag[s][0] = (_Float16)p0.x; afrag[s][1] = (_Float16)p0.y;
        afrag[s][2] = (_Float16)p0.z; afrag[s][3] = (_Float16)p0.w;
        afrag[s][4] = (_Float16)p1.x; afrag[s][5] = (_Float16)p1.y;
        afrag[s][6] = (_Float16)p1.z; afrag[s][7] = (_Float16)p1.w;
    }

    const half8* bp = (const half8*)w1s;
    f32x4 acc[8];
#pragma unroll
    for (int c = 0; c < 8; ++c) acc[c] = (f32x4){0.f, 0.f, 0.f, 0.f};
#pragma unroll
    for (int c = 0; c < 8; ++c)
#pragma unroll
        for (int s = 0; s < 4; ++s)
            acc[c] = __builtin_amdgcn_mfma_f32_16x16x32_f16(afrag[s], bp[(c * 4 + s) * 64 + lane], acc[c], 0, 0, 0);

#pragma unroll
    for (int i = 0; i < 4; ++i) {
        int row = rowbase + quad * 4 + i;
        if (row < n) {
            float w = dinv[row];
            unsigned char* yr = Y8 + (size_t)row * 128 + m;
#pragma unroll
            for (int c = 0; c < 8; ++c) yr[c * 16] = f32_to_fp8(acc[c][i] * w);
        }
    }
}

// --- GEMM2 (MFMA): Y8[r,64] = fp8( dinv[r] * (Xh[r,128] @ W2) ), X fp16 ----
__global__ __launch_bounds__(256) void gemm2_mfma_kernel(const __half* __restrict__ X,
                                                         const __half* __restrict__ w2s,
                                                         const float* __restrict__ dinv,
                                                         unsigned char* __restrict__ Y8, int n) {
    int t = threadIdx.x;
    int wave = t >> 6, lane = t & 63;
    int quad = lane >> 4, m = lane & 15;
    int rowbase = blockIdx.x * 64 + wave * 16;
    int arow = rowbase + m;
    bool aok = arow < n;
    const __half* xr = X + (size_t)arow * 128 + quad * 8;

    half8 afrag[4];
#pragma unroll
    for (int s = 0; s < 4; ++s) {
        if (aok) afrag[s] = *(const half8*)(xr + s * 32);
        else     afrag[s] = (half8){0, 0, 0, 0, 0, 0, 0, 0};
    }

    const half8* bp = (const half8*)w2s;
    f32x4 acc[4];
#pragma unroll
    for (int c = 0; c < 4; ++c) acc[c] = (f32x4){0.f, 0.f, 0.f, 0.f};
#pragma unroll
    for (int c = 0; c < 4; ++c)
#pragma unroll
        for (int s = 0; s < 4; ++s)
            acc[c] = __builtin_amdgcn_mfma_f32_16x16x32_f16(afrag[s], bp[(c * 4 + s) * 64 + lane], acc[c], 0, 0, 0);

#pragma unroll
    for (int i = 0; i < 4; ++i) {
        int row = rowbase + quad * 4 + i;
        if (row < n) {
            float w = dinv[row];
            unsigned char* yr = Y8 + (size_t)row * 64 + m;
#pragma unroll
            for (int c = 0; c < 4; ++c) yr[c * 16] = f32_to_fp8(acc[c][i] * w);
        }
    }
}

// --- pull layer 1: H[d] = relu(dinv[d]*(T'[d] + sum T'[col]) + b1), F=128 --
// R19: 4 nodes/wave. Quarter (16 lanes) owns a node; lane f holds features
// f*8..f*8+7 (8B of the 128B fp8 row). No cross-lane reduce. Finished
// quarters gather the self row (L1-hot) and cndmask to zero.
__global__ __launch_bounds__(256) void pull_agg1_kernel(const unsigned char* __restrict__ T8,
                                                        const int* __restrict__ col,
                                                        const unsigned int* __restrict__ cursor,
                                                        const unsigned int* __restrict__ deg,
                                                        const float* __restrict__ dinv,
                                                        const float* __restrict__ b1,
                                                        __half* __restrict__ H, int N) {
    int wid = blockIdx.x * 4 + (threadIdx.x >> 6);
    int lane = threadIdx.x & 63;
    int q = lane >> 4, f = lane & 15;
    int node = wid * 4 + q;
    bool act = node < N;
    unsigned int nodeC = (unsigned int)(act ? node : (N - 1));
    unsigned int end = cursor[nodeC];
    unsigned int e = end - deg[nodeC];
    if (!act) e = end;
    unsigned int boff = (unsigned int)f << 3;       // 8B per lane

    float acc[8];
    {   // self term
        const unsigned int* rp = (const unsigned int*)(T8 + nodeC * 128u + boff);
        unsigned int w0 = rp[0], w1 = rp[1];
        auto f0 = __builtin_amdgcn_cvt_pk_f32_fp8((int)w0, false);
        auto f1 = __builtin_amdgcn_cvt_pk_f32_fp8((int)w0, true);
        auto f2 = __builtin_amdgcn_cvt_pk_f32_fp8((int)w1, false);
        auto f3 = __builtin_amdgcn_cvt_pk_f32_fp8((int)w1, true);
        acc[0] = f0[0]; acc[1] = f0[1]; acc[2] = f1[0]; acc[3] = f1[1];
        acc[4] = f2[0]; acc[5] = f2[1]; acc[6] = f3[0]; acc[7] = f3[1];
    }

    while (__any(e < end)) {                        // 8 edges/quarter/iter
        unsigned int s[8];
#pragma unroll
        for (int k = 0; k < 8; ++k) s[k] = (unsigned int)col[e + k];  // quarter-uniform addr
#pragma unroll
        for (int k = 0; k < 8; ++k) {
            bool ok = (e + k) < end;
            unsigned int idx = ok ? min(s[k], (unsigned int)(N - 1)) : nodeC;
            const unsigned int* rp = (const unsigned int*)(T8 + idx * 128u + boff);
            unsigned int v0 = rp[0], v1 = rp[1];
            v0 = ok ? v0 : 0u;
            v1 = ok ? v1 : 0u;
            fp8x4_acc(v0, acc);
            fp8x4_acc(v1, acc + 4);
        }
        e += 8u;
    }

    if (act) {
        float dv = dinv[node];
        const float4* bp = (const float4*)b1;       // features f*8..f*8+7
        float4 ba = bp[2 * f], bb = bp[2 * f + 1];
        __half2 h0 = __floats2half2_rn(fmaxf(fmaf(dv, acc[0], ba.x), 0.f),
                                       fmaxf(fmaf(dv, acc[1], ba.y), 0.f));
        __half2 h1 = __floats2half2_rn(fmaxf(fmaf(dv, acc[2], ba.z), 0.f),
                                       fmaxf(fmaf(dv, acc[3], ba.w), 0.f));
        __half2 h2 = __floats2half2_rn(fmaxf(fmaf(dv, acc[4], bb.x), 0.f),
                                       fmaxf(fmaf(dv, acc[5], bb.y), 0.f));
        __half2 h3 = __floats2half2_rn(fmaxf(fmaf(dv, acc[6], bb.z), 0.f),
                                       fmaxf(fmaf(dv, acc[7], bb.w), 0.f));
        uint4 st;
        st.x = *(unsigned int*)&h0; st.y = *(unsigned int*)&h1;
        st.z = *(unsigned int*)&h2; st.w = *(unsigned int*)&h3;
        *(uint4*)((char*)H + (size_t)node * 256 + f * 16) = st;
    }
}

// --- pull layer 2 + logsoftmax: out[d] = lsm(dinv[d]*sum + b2), F=64 -------
// R19: 4 nodes/wave. Quarter owns a node; lane f holds features f*4..f*4+3
// (4B of the 64B fp8 row). Softmax via shfl_xor within the 16-lane quarter.
__global__ __launch_bounds__(256) void pull_agg2_kernel(const unsigned char* __restrict__ T8,
                                                        const int* __restrict__ col,
                                                        const unsigned int* __restrict__ cursor,
                                                        const unsigned int* __restrict__ deg,
                                                        const float* __restrict__ dinv,
                                                        const float* __restrict__ b2,
                                                        float* __restrict__ OUT, int N) {
    int wid = blockIdx.x * 4 + (threadIdx.x >> 6);
    int lane = threadIdx.x & 63;
    int q = lane >> 4, f = lane & 15;
    int node = wid * 4 + q;
    bool act = node < N;
    unsigned int nodeC = (unsigned int)(act ? node : (N - 1));
    unsigned int end = cursor[nodeC];
    unsigned int e = end - deg[nodeC];
    if (!act) e = end;
    unsigned int boff = (unsigned int)f << 2;       // 4B per lane

    float acc[4];
    {   // self term
        unsigned int w0 = *(const unsigned int*)(T8 + nodeC * 64u + boff);
        auto f0 = __builtin_amdgcn_cvt_pk_f32_fp8((int)w0, false);
        auto f1 = __builtin_amdgcn_cvt_pk_f32_fp8((int)w0, true);
        acc[0] = f0[0]; acc[1] = f0[1]; acc[2] = f1[0]; acc[3] = f1[1];
    }

    while (__any(e < end)) {                        // 8 edges/quarter/iter
        unsigned int s[8];
#pragma unroll
        for (int k = 0; k < 8; ++k) s[k] = (unsigned int)col[e + k];
#pragma unroll
        for (int k = 0; k < 8; ++k) {
            bool ok = (e + k) < end;
            unsigned int idx = ok ? min(s[k], (unsigned int)(N - 1)) : nodeC;
            unsigned int v = *(const unsigned int*)(T8 + idx * 64u + boff);
            v = ok ? v : 0u;
            fp8x4_acc(v, acc);
        }
        e += 8u;
    }

    float dv = dinv[nodeC];
    float4 bb = ((const float4*)b2)[f];
    float v0 = fmaf(dv, acc[0], bb.x);
    float v1 = fmaf(dv, acc[1], bb.y);
    float v2 = fmaf(dv, acc[2], bb.z);
    float v3 = fmaf(dv, acc[3], bb.w);
    float m = fmaxf(fmaxf(v0, v1), fmaxf(v2, v3));
#pragma unroll
    for (int off = 1; off < 16; off <<= 1) m = fmaxf(m, __shfl_xor(m, off));
    float sum = __expf(v0 - m) + __expf(v1 - m) + __expf(v2 - m) + __expf(v3 - m);
#pragma unroll
    for (int off = 1; off < 16; off <<= 1) sum += __shfl_xor(sum, off);
    float ls = m + logf(sum);
    if (act)
        ((float4*)OUT)[(size_t)node * 16 + f] =
            make_float4(v0 - ls, v1 - ls, v2 - ls, v3 - ls);
}

extern "C" void kernel_launch(void* const* d_in, const int* in_sizes, int n_in,
                              void* d_out, int out_size, void* d_ws, size_t ws_size,
                              hipStream_t stream) {
    const float* x   = (const float*)d_in[0];
    const int*   ei  = (const int*)d_in[1];   // int32 per harness contract
    const float* W1  = (const float*)d_in[2];
    const float* b1  = (const float*)d_in[3];
    const float* W2  = (const float*)d_in[4];
    const float* b2  = (const float*)d_in[5];
    float*       out = (float*)d_out;

    const int N = in_sizes[0] / 128;      // 100000
    const int E = in_sizes[1] / 2;        // 1600000
    const int* src = ei;
    const int* dst = ei + E;
    const int NB = (N + BSIZE - 1) >> BSHIFT;   // dst buckets (196 <= 256)
    const size_t CAPTOT = (size_t)NB << CAPSHIFT;

    // workspace layout
    char* ws = (char*)d_ws;
    size_t off = 0;
    auto alloc = [&](size_t bytes) { void* p = ws + off; off = (off + bytes + 255) & ~(size_t)255; return p; };
    unsigned int* deg    = (unsigned int*)alloc((size_t)N * 4);
    float*        dinv   = (float*)alloc((size_t)N * 4);
    unsigned int* cursor = (unsigned int*)alloc((size_t)N * 4);
    unsigned int* bf     = (unsigned int*)alloc(256 * 4);       // bucket_fill
    __half*       w1s    = (__half*)alloc(128 * 128 * 2);       // swizzled W1
    __half*       w2s    = (__half*)alloc(128 * 64 * 2);        // swizzled W2
    int*          col    = (int*)alloc(CAPTOT * 4 + 256);       // CAP-strided (+overrun pad)
    unsigned char* A     = (unsigned char*)alloc((size_t)N * 128); // T1'/T2' fp8
    __half*       B      = (__half*)alloc((size_t)N * 128 * 2);    // h fp16
    unsigned int* ebuf   = (unsigned int*)alloc(CAPTOT * 4);

    // 1. CSR build: partition into fixed-capacity buckets -> per-bucket scatter
    hipMemsetAsync(bf, 0, 256 * 4, stream);
    partition_kernel<<<(E + P2_T * P2_I - 1) / (P2_T * P2_I), P2_T, 0, stream>>>(src, dst, bf, ebuf, E, NB);
    bucket_scatter2_kernel<<<NB, 256, 0, stream>>>(ebuf, bf, cursor, deg, dinv, col, N);
    // now cursor[i] == rowend(i); rowstart(i) = cursor[i] - deg[i]; dinv ready

    // 1b. swizzle weights into MFMA fragment order
    swizzle_w_kernel<<<64, 256, 0, stream>>>(W1, W2, w1s, w2s);

    // 2. T1' = fp8(dinv * (x @ W1)) [MFMA];  h = relu(dinv*(pull) + b1)
    gemm1_mfma_kernel<<<(N + 63) / 64, 256, 0, stream>>>(x, w1s, dinv, A, N);
    pull_agg1_kernel<<<(N + 15) / 16, 256, 0, stream>>>(A, col, cursor, deg, dinv, b1, B, N);

    // 3. T2' = fp8(dinv * (h @ W2)) [MFMA];  out = logsoftmax(dinv*(pull) + b2)
    gemm2_mfma_kernel<<<(N + 63) / 64, 256, 0, stream>>>(B, w2s, dinv, A, N);
    pull_agg2_kernel<<<(N + 15) / 16, 256, 0, stream>>>(A, col, cursor, deg, dinv, b2, out, N);
}